// Round 11
// baseline (170.313 us; speedup 1.0000x reference)
//
#include <hip/hip_runtime.h>
#include <hip/hip_bf16.h>
#include <math.h>

// Problem constants (B,S,D,E = 2,2048,1024,8)
#define Bq 2
#define Sq 2048
#define Dq 1024
#define Eq 8
#define Hq 2048            // 2*D
#define Aq 128             // H/16
#define Nq (Bq*Sq)         // 4096 tokens

typedef __attribute__((ext_vector_type(4))) float f32x4;
typedef __attribute__((ext_vector_type(8))) short bfrag;   // 8 bf16 in 4 VGPRs

__device__ __forceinline__ float silu_f(float x) {
    return x / (1.0f + expf(-x));
}
__device__ __forceinline__ unsigned short f2bf(float x) {  // RNE fp32->bf16
    unsigned u = __float_as_uint(x);
    u += 0x7fffu + ((u >> 16) & 1u);
    return (unsigned short)(u >> 16);
}
__device__ __forceinline__ float bf2f(unsigned short h) {
    return __uint_as_float(((unsigned)h) << 16);
}
__device__ __forceinline__ void gl16(const unsigned short* g, unsigned short* l) {
    __builtin_amdgcn_global_load_lds(
        (const __attribute__((address_space(1))) void*)g,
        (__attribute__((address_space(3))) void*)(void*)l, 16, 0, 0);
}

// Counted-vmcnt wait-then-barrier (T4). vmcnt retires IN ORDER, so with two
// stages outstanding, vmcnt(N_one_stage) drains exactly the oldest stage.
#define WAITV_BAR(N)                                            \
    asm volatile("s_waitcnt vmcnt(" #N ")" ::: "memory");       \
    __builtin_amdgcn_s_barrier();                               \
    asm volatile("" ::: "memory")
#define END_BAR()                                               \
    asm volatile("" ::: "memory");                              \
    __builtin_amdgcn_s_barrier();                               \
    asm volatile("" ::: "memory")

// ---------------------------------------------------------------------------
// BK=64 staging/fragment scheme (shared by mg/gup/gfinal):
//  Panel = [128 rows][64 cols] bf16 = 16 KB, staged in 4 gl16 rounds.
//  LDS(row, q) holds G(row, q ^ (row&7)) -> pre-swizzled global source,
//  linear LDS dest, conflict-free ds_read_b128 (verified: bank conflicts = 0).
// ---------------------------------------------------------------------------

__global__ __launch_bounds__(256)
void convert_all(const float* __restrict__ x,  const float* __restrict__ gw,
                 const float* __restrict__ uw, const float* __restrict__ dw,
                 const float* __restrict__ pw, const float* __restrict__ ow,
                 const float* __restrict__ opw, const float* __restrict__ aw,
                 unsigned short* xh,  unsigned short* gwh, unsigned short* uwh,
                 unsigned short* dwh, unsigned short* pwh, unsigned short* powh,
                 unsigned short* oph, unsigned short* adw)
{
    const int T = 3276800;
    for (int i = blockIdx.x * 256 + threadIdx.x; i < T; i += gridDim.x * 256) {
        const float* in; unsigned short* hi; int j = i;
        if (j < 1048576)                 { in = x;   hi = xh;  }
        else if ((j -= 1048576) < 524288){ in = gw;  hi = gwh; }
        else if ((j -= 524288) < 524288) { in = uw;  hi = uwh; }
        else if ((j -= 524288) < 524288) { in = dw;  hi = dwh; }
        else if ((j -= 524288) < 32768)  { in = pw;  hi = pwh; }
        else if ((j -= 32768) < 65536)   { in = ow;  hi = powh; }
        else if ((j -= 65536) < 524288)  { in = opw; hi = oph; }
        else { j -= 524288;                in = aw;  hi = adw; }
        float4 v = ((const float4*)in)[j];
        ((ushort4*)hi)[j] = make_ushort4(f2bf(v.x), f2bf(v.y), f2bf(v.z), f2bf(v.w));
    }
}

// Transpose [R][C] -> bf16 [C][R], batched by blockIdx.z.
template<typename TIN>
__global__ __launch_bounds__(256)
void transb(const TIN* __restrict__ in, unsigned short* __restrict__ out, int R, int C)
{
    __shared__ float t[32][33];
    in  += (size_t)blockIdx.z * R * C;
    out += (size_t)blockIdx.z * R * C;
    int tx = threadIdx.x & 31, ty = threadIdx.x >> 5;
    int r0 = blockIdx.y * 32, c0 = blockIdx.x * 32;
#pragma unroll
    for (int j = 0; j < 4; j++) {
        TIN v = in[(size_t)(r0 + ty + j * 8) * C + c0 + tx];
        float f;
        if (sizeof(TIN) == 2) f = bf2f(*(const unsigned short*)&v);
        else                  f = *(const float*)&v;
        t[ty + j * 8][tx] = f;
    }
    __syncthreads();
#pragma unroll
    for (int j = 0; j < 4; j++)
        out[(size_t)(c0 + ty + j * 8) * R + r0 + tx] = f2bf(t[tx][ty + j * 8]);
}

// ---------------------------------------------------------------------------
// 1-term bf16 MFMA GEMM, BK=64, 2-buf + counted-vmcnt (round-10 proven; kept:
// 64 KB LDS -> 2 blocks/CU cross-block overlap helps the narrow split-K shapes).
// EPI: 0 = fp32 store (+bz*zC+kz*pz); 1 = bf16 silu-clip store (+bz*zC).
// ---------------------------------------------------------------------------
template<int EPI>
__global__ __launch_bounds__(256)
void mg(const unsigned short* __restrict__ Ah, const unsigned short* __restrict__ Bh,
        void* __restrict__ Cv, int N, int K, int kchunks,
        long zA, long zB, long zC, long pz)
{
    __shared__ __align__(16) unsigned short lds[32768];  // 2 bufs x (A 8192 | B 8192)

    const int tid = threadIdx.x;
    const int l   = tid & 63;
    const int w   = tid >> 6;
    const int wr  = w >> 1, wc = w & 1;
    const int bm0 = blockIdx.y * 128, bn0 = blockIdx.x * 128;
    const int bz  = blockIdx.z / kchunks;
    const int kz  = blockIdx.z - bz * kchunks;
    const int kcnt = K / kchunks;
    const int kbeg = kz * kcnt;
    const int kend = kbeg + kcnt;

    const unsigned short* A0 = Ah + (size_t)bz * zA;
    const unsigned short* B0 = Bh + (size_t)bz * zB;

    const int srow = tid >> 3;                 // 0..31 (+32 per round)
    const int sq   = (tid & 7) ^ (srow & 7);
    const size_t aoff = (size_t)(bm0 + srow) * K + sq * 8;
    const size_t boff = (size_t)(bn0 + srow) * K + sq * 8;
    const size_t r32  = (size_t)32 * K;

    auto stage = [&](int b, int kt) {
        unsigned short* d = &lds[b * 16384 + (w << 9)];
        gl16(A0 + aoff + kt,           d + 0);
        gl16(A0 + aoff + kt + r32,     d + 2048);
        gl16(A0 + aoff + kt + 2 * r32, d + 4096);
        gl16(A0 + aoff + kt + 3 * r32, d + 6144);
        gl16(B0 + boff + kt,           d + 8192);
        gl16(B0 + boff + kt + r32,     d + 10240);
        gl16(B0 + boff + kt + 2 * r32, d + 12288);
        gl16(B0 + boff + kt + 3 * r32, d + 14336);
    };

    const int rowa = (wr * 64 + (l & 15)) * 64;   // ushort offset of A row
    const int rowb = (wc * 64 + (l & 15)) * 64;
    const int q0 = (((l >> 4)    ) ^ (l & 7)) << 3;   // ks=0 slot*8
    const int q1 = (((l >> 4) + 4) ^ (l & 7)) << 3;   // ks=1 slot*8

    f32x4 acc[4][4];
#pragma unroll
    for (int i = 0; i < 4; i++)
#pragma unroll
        for (int j = 0; j < 4; j++) acc[i][j] = (f32x4){0.f, 0.f, 0.f, 0.f};

    stage(0, kbeg);
    int cur = 0;
    for (int kt = kbeg; kt < kend; kt += 64) {
        if (kt + 64 < kend) {
            stage(cur ^ 1, kt + 64);       // next tile's 8 loads stay in flight
            WAITV_BAR(8);                  // wait only for CUR's loads
        } else {
            WAITV_BAR(0);
        }
        const int cb = cur * 16384;
#pragma unroll
        for (int ks = 0; ks < 2; ks++) {
            const int qo = ks ? q1 : q0;
            bfrag a4[4], b4[4];
#pragma unroll
            for (int f = 0; f < 4; f++) {
                a4[f] = *(const bfrag*)&lds[cb +        rowa + f * 1024 + qo];
                b4[f] = *(const bfrag*)&lds[cb + 8192 + rowb + f * 1024 + qo];
            }
#pragma unroll
            for (int i = 0; i < 4; i++)
#pragma unroll
                for (int j = 0; j < 4; j++)
                    acc[i][j] = __builtin_amdgcn_mfma_f32_16x16x32_bf16(a4[i], b4[j], acc[i][j], 0, 0, 0);
        }
        END_BAR();                         // readers done before next overwrite
        cur ^= 1;
    }

    const int crow0 = bm0 + wr * 64 + (l >> 4) * 4;
    const int ccol0 = bn0 + wc * 64 + (l & 15);
#pragma unroll
    for (int i = 0; i < 4; i++)
#pragma unroll
        for (int j = 0; j < 4; j++)
#pragma unroll
            for (int r = 0; r < 4; r++) {
                size_t idx = (size_t)(crow0 + i * 16 + r) * N + (ccol0 + j * 16);
                float v = acc[i][j][r];
                if (EPI == 0)
                    ((float*)Cv + (size_t)bz * zC + (size_t)kz * pz)[idx] = v;
                else
                    ((unsigned short*)Cv + (size_t)bz * zC)[idx] =
                        f2bf(silu_f(fminf(fmaxf(v, -5.f), 5.f)));
            }
}

// ---------------------------------------------------------------------------
// Fused gate+up GEMM, BK=64, 3-DEEP ring + single barrier/K-step (prefetch
// distance 2: each tile gets two compute phases to land; 144 KB LDS is free
// at the existing 1 block/CU). Buffer-reuse race closed by staging AFTER the
// rendezvous barrier: stage(i+2) overwrites buf((i-1)%3) whose readers all
// passed this barrier. 2D XCD chunk (proven: FETCH 70->41 MB).
//   hh[n,h] = bf16( silu(x@gw^T) * (x@uw^T) )      K=1024.
// ---------------------------------------------------------------------------
__global__ __launch_bounds__(256)
void gup(const unsigned short* __restrict__ xh, const unsigned short* __restrict__ gwh,
         const unsigned short* __restrict__ uwh, unsigned short* __restrict__ hh)
{
    __shared__ __align__(16) unsigned short lds[73728];  // 3 bufs x (x|gw|uw 24576)
    const int tid = threadIdx.x;
    const int l   = tid & 63;
    const int w   = tid >> 6;
    const int wr  = w >> 1, wc = w & 1;

    int id  = blockIdx.y * gridDim.x + blockIdx.x;
    int xcd = id & 7, j = id >> 3;
    int bx  = (xcd & 1) * 8 + (j & 7);
    int by  = (xcd >> 1) * 8 + (j >> 3);
    const int bm0 = by * 128, bn0 = bx * 128;

    const int srow = tid >> 3;
    const int sq   = (tid & 7) ^ (srow & 7);
    const size_t aoff = (size_t)(bm0 + srow) * Dq + sq * 8;
    const size_t boff = (size_t)(bn0 + srow) * Dq + sq * 8;
    const size_t r32  = (size_t)32 * Dq;

    const int rowa = (wr * 64 + (l & 15)) * 64;
    const int rowb = (wc * 64 + (l & 15)) * 64;
    const int q0 = (((l >> 4)    ) ^ (l & 7)) << 3;
    const int q1 = (((l >> 4) + 4) ^ (l & 7)) << 3;

    auto stage = [&](int b, int kt) {
        unsigned short* d = &lds[b * 24576 + (w << 9)];
        gl16(xh  + aoff + kt,           d + 0);
        gl16(xh  + aoff + kt + r32,     d + 2048);
        gl16(xh  + aoff + kt + 2 * r32, d + 4096);
        gl16(xh  + aoff + kt + 3 * r32, d + 6144);
        gl16(gwh + boff + kt,           d + 8192);
        gl16(gwh + boff + kt + r32,     d + 10240);
        gl16(gwh + boff + kt + 2 * r32, d + 12288);
        gl16(gwh + boff + kt + 3 * r32, d + 14336);
        gl16(uwh + boff + kt,           d + 16384);
        gl16(uwh + boff + kt + r32,     d + 18432);
        gl16(uwh + boff + kt + 2 * r32, d + 20480);
        gl16(uwh + boff + kt + 3 * r32, d + 22528);
    };

    f32x4 accg[4][4], accu[4][4];
#pragma unroll
    for (int i = 0; i < 4; i++)
#pragma unroll
        for (int jj = 0; jj < 4; jj++) {
            accg[i][jj] = (f32x4){0.f, 0.f, 0.f, 0.f};
            accu[i][jj] = (f32x4){0.f, 0.f, 0.f, 0.f};
        }

    stage(0, 0);
    stage(1, 64);
    int cur = 0;
    for (int kt = 0; kt < Dq; kt += 64) {
        // outstanding: buf(i) [oldest] + buf(i+1); in-order retire -> vmcnt(12)
        // drains exactly buf(i). Last iter: only buf(i) left -> vmcnt(0).
        if (kt + 64 < Dq) { WAITV_BAR(12); } else { WAITV_BAR(0); }
        if (kt + 128 < Dq) {
            int nb3 = (cur + 2 >= 3) ? cur - 1 : cur + 2;
            stage(nb3, kt + 128);          // overwrites buf((i-1)%3): safe post-barrier
        }
        const int cb = cur * 24576;
#pragma unroll
        for (int ks = 0; ks < 2; ks++) {
            const int qo = ks ? q1 : q0;
            bfrag a4[4], g4[4], u4[4];
#pragma unroll
            for (int f = 0; f < 4; f++) {
                a4[f] = *(const bfrag*)&lds[cb +         rowa + f * 1024 + qo];
                g4[f] = *(const bfrag*)&lds[cb +  8192 + rowb + f * 1024 + qo];
                u4[f] = *(const bfrag*)&lds[cb + 16384 + rowb + f * 1024 + qo];
            }
#pragma unroll
            for (int i = 0; i < 4; i++)
#pragma unroll
                for (int jj = 0; jj < 4; jj++) {
                    accg[i][jj] = __builtin_amdgcn_mfma_f32_16x16x32_bf16(a4[i], g4[jj], accg[i][jj], 0, 0, 0);
                    accu[i][jj] = __builtin_amdgcn_mfma_f32_16x16x32_bf16(a4[i], u4[jj], accu[i][jj], 0, 0, 0);
                }
        }
        cur = (cur == 2) ? 0 : cur + 1;
    }

    const int crow0 = bm0 + wr * 64 + (l >> 4) * 4;
    const int ccol0 = bn0 + wc * 64 + (l & 15);
#pragma unroll
    for (int i = 0; i < 4; i++)
#pragma unroll
        for (int jj = 0; jj < 4; jj++)
#pragma unroll
            for (int r = 0; r < 4; r++) {
                size_t idx = (size_t)(crow0 + i * 16 + r) * Hq + (ccol0 + jj * 16);
                hh[idx] = f2bf(silu_f(accg[i][jj][r]) * accu[i][jj][r]);
            }
}

// ---------------------------------------------------------------------------
// Final fused GEMM, BK=64, 3-DEEP ring + single barrier/K-step (96 KB LDS,
// grid=256=1 block/CU so depth is free):  out[4096][1024] =
//   hh@dwh^T (K=2048)  +  acat@kcat^T (K=256)
// ---------------------------------------------------------------------------
__global__ __launch_bounds__(256)
void gfinal(const unsigned short* __restrict__ hh, const unsigned short* __restrict__ dwh,
            const unsigned short* __restrict__ acat, const unsigned short* __restrict__ kcat,
            float* __restrict__ out)
{
    __shared__ __align__(16) unsigned short lds[49152];  // 3 bufs x 16384
    const int tid = threadIdx.x;
    const int l   = tid & 63;
    const int w   = tid >> 6;
    const int wr  = w >> 1, wc = w & 1;

    int nb  = gridDim.x * gridDim.y;                      // 256
    int id  = blockIdx.y * gridDim.x + blockIdx.x;
    int id2 = (id & 7) * (nb >> 3) + (id >> 3);
    int bx  = id2 % gridDim.x, by = id2 / gridDim.x;
    const int bm0 = by * 128, bn0 = bx * 128;

    const int srow = tid >> 3;
    const int sq   = (tid & 7) ^ (srow & 7);
    const int rowa = (wr * 64 + (l & 15)) * 64;
    const int rowb = (wc * 64 + (l & 15)) * 64;
    const int q0 = (((l >> 4)    ) ^ (l & 7)) << 3;
    const int q1 = (((l >> 4) + 4) ^ (l & 7)) << 3;

    f32x4 acc[4][4];
#pragma unroll
    for (int i = 0; i < 4; i++)
#pragma unroll
        for (int j = 0; j < 4; j++) acc[i][j] = (f32x4){0.f, 0.f, 0.f, 0.f};

    // ---- main: K=2048, 3-deep ----
    {
        const size_t aoff = (size_t)(bm0 + srow) * Hq + sq * 8;
        const size_t boff = (size_t)(bn0 + srow) * Hq + sq * 8;
        const size_t r32  = (size_t)32 * Hq;
        auto stage = [&](int b, int kt) {
            unsigned short* d = &lds[b * 16384 + (w << 9)];
            gl16(hh  + aoff + kt,           d + 0);
            gl16(hh  + aoff + kt + r32,     d + 2048);
            gl16(hh  + aoff + kt + 2 * r32, d + 4096);
            gl16(hh  + aoff + kt + 3 * r32, d + 6144);
            gl16(dwh + boff + kt,           d + 8192);
            gl16(dwh + boff + kt + r32,     d + 10240);
            gl16(dwh + boff + kt + 2 * r32, d + 12288);
            gl16(dwh + boff + kt + 3 * r32, d + 14336);
        };
        stage(0, 0);
        stage(1, 64);
        int cur = 0;
        for (int kt = 0; kt < Hq; kt += 64) {
            if (kt + 64 < Hq) { WAITV_BAR(8); } else { WAITV_BAR(0); }
            if (kt + 128 < Hq) {
                int nb3 = (cur + 2 >= 3) ? cur - 1 : cur + 2;
                stage(nb3, kt + 128);
            }
            const int cb = cur * 16384;
#pragma unroll
            for (int ks = 0; ks < 2; ks++) {
                const int qo = ks ? q1 : q0;
                bfrag a4[4], b4[4];
#pragma unroll
                for (int f = 0; f < 4; f++) {
                    a4[f] = *(const bfrag*)&lds[cb +        rowa + f * 1024 + qo];
                    b4[f] = *(const bfrag*)&lds[cb + 8192 + rowb + f * 1024 + qo];
                }
#pragma unroll
                for (int i = 0; i < 4; i++)
#pragma unroll
                    for (int j = 0; j < 4; j++)
                        acc[i][j] = __builtin_amdgcn_mfma_f32_16x16x32_bf16(a4[i], b4[j], acc[i][j], 0, 0, 0);
            }
            cur = (cur == 2) ? 0 : cur + 1;
        }
    }
    END_BAR();   // all waves done with main's last compute before tail staging
    // ---- tail: K=256 over [acat | kcat], 3-deep (4 iters) ----
    {
        const size_t aoff = (size_t)(bm0 + srow) * 256 + sq * 8;
        const size_t boff = (size_t)(bn0 + srow) * 256 + sq * 8;
        const size_t r32  = (size_t)32 * 256;
        auto stage2 = [&](int b, int kt) {
            unsigned short* d = &lds[b * 16384 + (w << 9)];
            gl16(acat + aoff + kt,           d + 0);
            gl16(acat + aoff + kt + r32,     d + 2048);
            gl16(acat + aoff + kt + 2 * r32, d + 4096);
            gl16(acat + aoff + kt + 3 * r32, d + 6144);
            gl16(kcat + boff + kt,           d + 8192);
            gl16(kcat + boff + kt + r32,     d + 10240);
            gl16(kcat + boff + kt + 2 * r32, d + 12288);
            gl16(kcat + boff + kt + 3 * r32, d + 14336);
        };
        stage2(0, 0);
        stage2(1, 64);
        int cur = 0;
        for (int kt = 0; kt < 256; kt += 64) {
            if (kt + 64 < 256) { WAITV_BAR(8); } else { WAITV_BAR(0); }
            if (kt + 128 < 256) {
                int nb3 = (cur + 2 >= 3) ? cur - 1 : cur + 2;
                stage2(nb3, kt + 128);
            }
            const int cb = cur * 16384;
#pragma unroll
            for (int ks = 0; ks < 2; ks++) {
                const int qo = ks ? q1 : q0;
                bfrag a4[4], b4[4];
#pragma unroll
                for (int f = 0; f < 4; f++) {
                    a4[f] = *(const bfrag*)&lds[cb +        rowa + f * 1024 + qo];
                    b4[f] = *(const bfrag*)&lds[cb + 8192 + rowb + f * 1024 + qo];
                }
#pragma unroll
                for (int i = 0; i < 4; i++)
#pragma unroll
                    for (int j = 0; j < 4; j++)
                        acc[i][j] = __builtin_amdgcn_mfma_f32_16x16x32_bf16(a4[i], b4[j], acc[i][j], 0, 0, 0);
            }
            cur = (cur == 2) ? 0 : cur + 1;
        }
    }

    const int crow0 = bm0 + wr * 64 + (l >> 4) * 4;
    const int ccol0 = bn0 + wc * 64 + (l & 15);
#pragma unroll
    for (int i = 0; i < 4; i++)
#pragma unroll
        for (int j = 0; j < 4; j++)
#pragma unroll
            for (int r = 0; r < 4; r++)
                out[(size_t)(crow0 + i * 16 + r) * Dq + ccol0 + j * 16] = acc[i][j][r];
}

// Reduce NZ split-K partials + LayerNorm over A=128 -> bf16.
template<int NZ>
__global__ __launch_bounds__(256)
void rln(const float* __restrict__ p, unsigned short* __restrict__ oh,
         const float* __restrict__ g, const float* __restrict__ b, long pstride)
{
    int row  = blockIdx.x * 4 + (threadIdx.x >> 6);
    int lane = threadIdx.x & 63;
    long base = (long)row * Aq;
    float x0 = 0.f, x1 = 0.f;
#pragma unroll
    for (int z = 0; z < NZ; z++) {
        x0 += p[base + z * pstride + lane];
        x1 += p[base + z * pstride + lane + 64];
    }
    float s  = x0 + x1;
    float ss = x0 * x0 + x1 * x1;
#pragma unroll
    for (int off = 32; off > 0; off >>= 1) {
        s  += __shfl_xor(s, off);
        ss += __shfl_xor(ss, off);
    }
    float m  = s * (1.0f / Aq);
    float v  = ss * (1.0f / Aq) - m * m;
    float rs = rsqrtf(v + 1e-5f);
    oh[base + lane]      = f2bf((x0 - m) * rs * g[lane]      + b[lane]);
    oh[base + lane + 64] = f2bf((x1 - m) * rs * g[lane + 64] + b[lane + 64]);
}

// Reduce NZ split-K partials [bz][NZ][rowsPerB][A] -> scaled bf16.
// Output col = ocol + bz*ocolStep (lets one launch fill both kcat halves).
template<int NZ>
__global__ __launch_bounds__(256)
void rbf(const float* __restrict__ p, unsigned short* __restrict__ o,
         int rowsPerB, float scale, int total, int ostride, int ocol, int ocolStep)
{
    int i = blockIdx.x * 256 + threadIdx.x;
    if (i >= total) return;
    int n = i >> 7, a = i & 127;
    int bz = n / rowsPerB, s = n - bz * rowsPerB;
    long base = ((long)bz * NZ) * rowsPerB * Aq + (long)s * Aq + a;
    float acc = 0.f;
#pragma unroll
    for (int z = 0; z < NZ; z++) acc += p[base + (long)z * rowsPerB * Aq];
    o[(long)s * ostride + (ocol + bz * ocolStep) + a +
      (ocolStep ? 0 : (long)bz * rowsPerB * ostride)] = f2bf(acc * scale);
}

// mixed[n,:] = sum_e ew[n,e] * LN_e(h[e,n,:])  -> bf16 into acat col 128.
__global__ __launch_bounds__(256)
void mix_ln(const float* __restrict__ h, const float* __restrict__ ew,
            const float* __restrict__ g, const float* __restrict__ bb,
            unsigned short* __restrict__ acat)
{
    int n    = blockIdx.x * 4 + (threadIdx.x >> 6);
    int lane = threadIdx.x & 63;
    float a0 = 0.0f, a1 = 0.0f;
#pragma unroll
    for (int e = 0; e < Eq; e++) {
        const float* r = h + ((long)e * Nq + n) * Aq;
        float x0 = r[lane], x1 = r[lane + 64];
        float s  = x0 + x1;
        float ss = x0 * x0 + x1 * x1;
#pragma unroll
        for (int off = 32; off > 0; off >>= 1) {
            s  += __shfl_xor(s, off);
            ss += __shfl_xor(ss, off);
        }
        float m  = s * (1.0f / Aq);
        float v  = ss * (1.0f / Aq) - m * m;
        float rs = rsqrtf(v + 1e-5f);
        float wv = ew[(long)n * Eq + e];
        a0 += wv * ((x0 - m) * rs * g[e * Aq + lane]      + bb[e * Aq + lane]);
        a1 += wv * ((x1 - m) * rs * g[e * Aq + lane + 64] + bb[e * Aq + lane + 64]);
    }
    acat[(long)n * 256 + 128 + lane]      = f2bf(a0);
    acat[(long)n * 256 + 128 + lane + 64] = f2bf(a1);
}

extern "C" void kernel_launch(void* const* d_in, const int* in_sizes, int n_in,
                              void* d_out, int out_size, void* d_ws, size_t ws_size,
                              hipStream_t stream)
{
    const float* x             = (const float*)d_in[0];
    const float* ew            = (const float*)d_in[1];
    const float* up_w          = (const float*)d_in[2];
    const float* gate_w        = (const float*)d_in[3];
    const float* down_w        = (const float*)d_in[4];
    const float* pre_w         = (const float*)d_in[5];
    const float* post_w        = (const float*)d_in[6];
    const float* an_g          = (const float*)d_in[7];
    const float* an_b          = (const float*)d_in[8];
    const float* adapt_proj_w  = (const float*)d_in[9];
    const float* adapter_w     = (const float*)d_in[10];
    const float* adapter_g     = (const float*)d_in[11];
    const float* adapter_b     = (const float*)d_in[12];
    const float* expert_proj_w = (const float*)d_in[13];
    const float* output_proj_w = (const float*)d_in[14];
    float* out = (float*)d_out;

    // ---- workspace (KB offsets; peak ~81 MB) ----
#define OFF(kb) ((char*)d_ws + (size_t)(kb) * 1024)
    float* kdp  = (float*)OFF(0);        // [16][D][A] 8MB   (phase 1, bz=0)
    float* wfp  = (float*)OFF(8192);     // 8MB              (phase 1, bz=1)
    float* p1   = (float*)OFF(16384);    // [8][N][A] 16MB   (phase 1)
    float* p2   = (float*)OFF(0);        // [8][N][A] 16MB   (phase 3)
    unsigned short* wmat = (unsigned short*)OFF(16384);  // [B][S][S] bf16 16MB (ph 3-4)
    float* p3   = (float*)OFF(0);        // [2][8][S][A] 16MB (phase 4)
    float* h_e  = (float*)OFF(0);        // [E][N][A] 16MB    (phase 5, after p3 dead)
    unsigned short* hh   = (unsigned short*)OFF(32768);  // [N,H] 16MB
    unsigned short* xh   = (unsigned short*)OFF(49152);  // 8MB
    unsigned short* gwh  = (unsigned short*)OFF(57344);  // 4MB
    unsigned short* uwh  = (unsigned short*)OFF(61440);  // 4MB
    unsigned short* dwh  = (unsigned short*)OFF(65536);  // 4MB   } contiguous pair
    unsigned short* oph  = (unsigned short*)OFF(69632);  // 4MB   } for batched kcat
    unsigned short* pwh  = (unsigned short*)OFF(73728);  // .25MB
    unsigned short* powh = (unsigned short*)OFF(73984);  // .5MB
    unsigned short* apT  = (unsigned short*)OFF(74496);  // .5MB  } contiguous pair
    unsigned short* epT  = (unsigned short*)OFF(75008);  // .5MB  }
    unsigned short* ainh = (unsigned short*)OFF(75520);  // 1MB
    unsigned short* ainT = (unsigned short*)OFF(76544);  // [B][A][S] 1MB
    unsigned short* aouth= (unsigned short*)OFF(77568);  // 1MB
    unsigned short* adw  = (unsigned short*)OFF(78592);  // .25MB
    unsigned short* kcat = (unsigned short*)OFF(78848);  // [D][256] .5MB
    unsigned short* acat = (unsigned short*)OFF(79360);  // [N][256] 2MB -> 81408
#undef OFF

    dim3 blk(256);
    const long NA = (long)Nq * Aq;
    const long SA = (long)Sq * Aq;
    const long SS = (long)Sq * Sq;

    // 1. conversions + transposes
    convert_all<<<dim3(2048), blk, 0, stream>>>(x, gate_w, up_w, down_w, pre_w, post_w,
        output_proj_w, adapter_w, xh, gwh, uwh, dwh, pwh, powh, oph, adw);
    transb<float><<<dim3(4, 64, 1), blk, 0, stream>>>(adapt_proj_w,  apT, Hq, Aq);
    transb<float><<<dim3(4, 64, 1), blk, 0, stream>>>(expert_proj_w, epT, Hq, Aq);

    // 2. weight fusions (batched bz=2): bz0 = dwh@apT -> kdp, bz1 = oph@epT -> wfp
    mg<0><<<dim3(1, 8, 32), blk, 0, stream>>>(dwh, apT, kdp, Aq, Hq, 16,
        (long)Dq * Hq, (long)Aq * Hq, (long)16 * Dq * Aq, (long)Dq * Aq);
    rbf<16><<<dim3(1024), blk, 0, stream>>>(kdp, kcat, Dq, 1.0f, 2 * Dq * Aq, 256, 0, 128);

    // 3. ain = LN(x @ pre_w^T)  (split-K 8)
    mg<0><<<dim3(1, 32, 8), blk, 0, stream>>>(xh, pwh, p1, Aq, Dq, 8, 0, 0, 0, NA);
    rln<8><<<dim3(1024), blk, 0, stream>>>(p1, ainh, an_g, an_b, NA);
    transb<unsigned short><<<dim3(4, 64, 2), blk, 0, stream>>>(ainh, ainT, Sq, Aq);

    // 4. fused SwiGLU: hh = bf16(silu(x@gw^T) * (x@uw^T))
    gup<<<dim3(16, 32), blk, 0, stream>>>(xh, gwh, uwh, hh);

    // 5. aout = LN(hidden @ post_w^T)  (split-K 8)
    mg<0><<<dim3(1, 32, 8), blk, 0, stream>>>(hh, powh, p2, Aq, Hq, 8, 0, 0, 0, NA);
    rln<8><<<dim3(1024), blk, 0, stream>>>(p2, aouth, an_g, an_b, NA);

    // 6. wmat = bf16(silu(clip(ain @ aout^T)))  per batch
    mg<1><<<dim3(16, 16, 2), blk, 0, stream>>>(ainh, aouth, wmat, Sq, Aq, 1,
        SA, SA, SS, 0);

    // 7. acat[:,0:128] = 0.1 * (wmat @ ain)  (split-K 8, batched)
    mg<0><<<dim3(1, 16, 16), blk, 0, stream>>>(wmat, ainT, p3, Aq, Sq, 8,
        SS, SA, 8 * SA, SA);
    rbf<8><<<dim3(2048), blk, 0, stream>>>(p3, acat, Sq, 0.1f, Nq * Aq, 256, 0, 0);

    // 8. expert path: h_e, then acat[:,128:256] = mixed
    mg<0><<<dim3(1, 32, 8), blk, 0, stream>>>(ainh, adw, h_e, Aq, Aq, 1,
        0, (long)Aq * Aq, NA, 0);
    mix_ln<<<dim3(1024), blk, 0, stream>>>(h_e, ew, adapter_g, adapter_b, acat);

    // 9. out = hh@dwh^T + acat@kcat^T
    gfinal<<<dim3(8, 32), blk, 0, stream>>>(hh, dwh, acat, kcat, out);
}

// Round 12
// 164.039 us; speedup vs baseline: 1.0382x; 1.0382x over previous
//
#include <hip/hip_runtime.h>
#include <hip/hip_bf16.h>
#include <math.h>

// Problem constants (B,S,D,E = 2,2048,1024,8)
#define Bq 2
#define Sq 2048
#define Dq 1024
#define Eq 8
#define Hq 2048            // 2*D
#define Aq 128             // H/16
#define Nq (Bq*Sq)         // 4096 tokens

typedef __attribute__((ext_vector_type(4))) float f32x4;
typedef __attribute__((ext_vector_type(8))) short bfrag;   // 8 bf16 in 4 VGPRs

__device__ __forceinline__ float silu_f(float x) {
    return x / (1.0f + expf(-x));
}
__device__ __forceinline__ unsigned short f2bf(float x) {  // RNE fp32->bf16
    unsigned u = __float_as_uint(x);
    u += 0x7fffu + ((u >> 16) & 1u);
    return (unsigned short)(u >> 16);
}
__device__ __forceinline__ float bf2f(unsigned short h) {
    return __uint_as_float(((unsigned)h) << 16);
}
__device__ __forceinline__ void gl16(const unsigned short* g, unsigned short* l) {
    __builtin_amdgcn_global_load_lds(
        (const __attribute__((address_space(1))) void*)g,
        (__attribute__((address_space(3))) void*)(void*)l, 16, 0, 0);
}

// Counted-vmcnt wait-then-barrier (T4). vmcnt retires IN ORDER.
#define WAITV_BAR(N)                                            \
    asm volatile("s_waitcnt vmcnt(" #N ")" ::: "memory");       \
    __builtin_amdgcn_s_barrier();                               \
    asm volatile("" ::: "memory")
#define END_BAR()                                               \
    asm volatile("" ::: "memory");                              \
    __builtin_amdgcn_s_barrier();                               \
    asm volatile("" ::: "memory")

// ---------------------------------------------------------------------------
// 512-thread / 8-wave BK=64 scheme (2M x 4N wave grid, wave tile 64x32):
//  Panel = [128 rows][64 cols] bf16 = 16 KB, staged in 2 gl16 rounds
//  (srow = tid>>3 in 0..63, +64 rows round 1; sq = (tid&7)^(srow&7)).
//  LDS(row,q) holds G(row, q^(row&7)); conflict-free ds_read_b128 (proven 0).
//  Reads: wave w: wr=w>>2 (64-row half), wc=w&3 (32-col quarter);
//  A frags i=0..3 at (wr*64+i*16+(l&15)); B frags j=0..1 at (wc*32+j*16+(l&15));
//  slot qo = ((ks*4+(l>>4))^(l&7))*8.
// ---------------------------------------------------------------------------

__global__ __launch_bounds__(256)
void convert_all(const float* __restrict__ x,  const float* __restrict__ gw,
                 const float* __restrict__ uw, const float* __restrict__ dw,
                 const float* __restrict__ pw, const float* __restrict__ ow,
                 const float* __restrict__ opw, const float* __restrict__ aw,
                 unsigned short* xh,  unsigned short* gwh, unsigned short* uwh,
                 unsigned short* dwh, unsigned short* pwh, unsigned short* powh,
                 unsigned short* oph, unsigned short* adw)
{
    const int T = 3276800;
    for (int i = blockIdx.x * 256 + threadIdx.x; i < T; i += gridDim.x * 256) {
        const float* in; unsigned short* hi; int j = i;
        if (j < 1048576)                 { in = x;   hi = xh;  }
        else if ((j -= 1048576) < 524288){ in = gw;  hi = gwh; }
        else if ((j -= 524288) < 524288) { in = uw;  hi = uwh; }
        else if ((j -= 524288) < 524288) { in = dw;  hi = dwh; }
        else if ((j -= 524288) < 32768)  { in = pw;  hi = pwh; }
        else if ((j -= 32768) < 65536)   { in = ow;  hi = powh; }
        else if ((j -= 65536) < 524288)  { in = opw; hi = oph; }
        else { j -= 524288;                in = aw;  hi = adw; }
        float4 v = ((const float4*)in)[j];
        ((ushort4*)hi)[j] = make_ushort4(f2bf(v.x), f2bf(v.y), f2bf(v.z), f2bf(v.w));
    }
}

// Transpose [R][C] -> bf16 [C][R], batched by blockIdx.z.
template<typename TIN>
__global__ __launch_bounds__(256)
void transb(const TIN* __restrict__ in, unsigned short* __restrict__ out, int R, int C)
{
    __shared__ float t[32][33];
    in  += (size_t)blockIdx.z * R * C;
    out += (size_t)blockIdx.z * R * C;
    int tx = threadIdx.x & 31, ty = threadIdx.x >> 5;
    int r0 = blockIdx.y * 32, c0 = blockIdx.x * 32;
#pragma unroll
    for (int j = 0; j < 4; j++) {
        TIN v = in[(size_t)(r0 + ty + j * 8) * C + c0 + tx];
        float f;
        if (sizeof(TIN) == 2) f = bf2f(*(const unsigned short*)&v);
        else                  f = *(const float*)&v;
        t[ty + j * 8][tx] = f;
    }
    __syncthreads();
#pragma unroll
    for (int j = 0; j < 4; j++)
        out[(size_t)(c0 + ty + j * 8) * R + r0 + tx] = f2bf(t[tx][ty + j * 8]);
}

// ---------------------------------------------------------------------------
// 1-term bf16 MFMA GEMM, BK=64, 8 waves, 2-buf + counted-vmcnt.
// 64 KB LDS -> 2 blocks/CU -> 4 waves/SIMD.
// EPI: 0 = fp32 store (+bz*zC+kz*pz); 1 = bf16 silu-clip store (+bz*zC).
// ---------------------------------------------------------------------------
template<int EPI>
__global__ __launch_bounds__(512)
void mg(const unsigned short* __restrict__ Ah, const unsigned short* __restrict__ Bh,
        void* __restrict__ Cv, int N, int K, int kchunks,
        long zA, long zB, long zC, long pz)
{
    __shared__ __align__(16) unsigned short lds[32768];  // 2 bufs x (A 8192 | B 8192)

    const int tid = threadIdx.x;
    const int l   = tid & 63;
    const int w   = tid >> 6;                  // 0..7
    const int wr  = w >> 2, wc = w & 3;
    const int bm0 = blockIdx.y * 128, bn0 = blockIdx.x * 128;
    const int bz  = blockIdx.z / kchunks;
    const int kz  = blockIdx.z - bz * kchunks;
    const int kcnt = K / kchunks;
    const int kbeg = kz * kcnt;
    const int kend = kbeg + kcnt;

    const unsigned short* A0 = Ah + (size_t)bz * zA;
    const unsigned short* B0 = Bh + (size_t)bz * zB;

    const int srow = tid >> 3;                 // 0..63 (+64 round 1)
    const int sq   = (tid & 7) ^ (srow & 7);
    const size_t aoff = (size_t)(bm0 + srow) * K + sq * 8;
    const size_t boff = (size_t)(bn0 + srow) * K + sq * 8;
    const size_t r64  = (size_t)64 * K;

    auto stage = [&](int b, int kt) {          // 4 gl16
        unsigned short* d = &lds[b * 16384 + (w << 9)];
        gl16(A0 + aoff + kt,       d + 0);
        gl16(A0 + aoff + kt + r64, d + 4096);
        gl16(B0 + boff + kt,       d + 8192);
        gl16(B0 + boff + kt + r64, d + 12288);
    };

    const int rowa = (wr * 64 + (l & 15)) * 64;
    const int rowb = (wc * 32 + (l & 15)) * 64;
    const int q0 = (((l >> 4)    ) ^ (l & 7)) << 3;
    const int q1 = (((l >> 4) + 4) ^ (l & 7)) << 3;

    f32x4 acc[4][2];
#pragma unroll
    for (int i = 0; i < 4; i++)
#pragma unroll
        for (int j = 0; j < 2; j++) acc[i][j] = (f32x4){0.f, 0.f, 0.f, 0.f};

    stage(0, kbeg);
    int cur = 0;
    for (int kt = kbeg; kt < kend; kt += 64) {
        if (kt + 64 < kend) {
            stage(cur ^ 1, kt + 64);
            WAITV_BAR(4);
        } else {
            WAITV_BAR(0);
        }
        const int cb = cur * 16384;
#pragma unroll
        for (int ks = 0; ks < 2; ks++) {
            const int qo = ks ? q1 : q0;
            bfrag a4[4], b4[2];
#pragma unroll
            for (int f = 0; f < 4; f++)
                a4[f] = *(const bfrag*)&lds[cb + rowa + f * 1024 + qo];
#pragma unroll
            for (int f = 0; f < 2; f++)
                b4[f] = *(const bfrag*)&lds[cb + 8192 + rowb + f * 1024 + qo];
#pragma unroll
            for (int i = 0; i < 4; i++)
#pragma unroll
                for (int j = 0; j < 2; j++)
                    acc[i][j] = __builtin_amdgcn_mfma_f32_16x16x32_bf16(a4[i], b4[j], acc[i][j], 0, 0, 0);
        }
        END_BAR();
        cur ^= 1;
    }

    const int crow0 = bm0 + wr * 64 + (l >> 4) * 4;
    const int ccol0 = bn0 + wc * 32 + (l & 15);
#pragma unroll
    for (int i = 0; i < 4; i++)
#pragma unroll
        for (int j = 0; j < 2; j++)
#pragma unroll
            for (int r = 0; r < 4; r++) {
                size_t idx = (size_t)(crow0 + i * 16 + r) * N + (ccol0 + j * 16);
                float v = acc[i][j][r];
                if (EPI == 0)
                    ((float*)Cv + (size_t)bz * zC + (size_t)kz * pz)[idx] = v;
                else
                    ((unsigned short*)Cv + (size_t)bz * zC)[idx] =
                        f2bf(silu_f(fminf(fmaxf(v, -5.f), 5.f)));
            }
}

// ---------------------------------------------------------------------------
// Fused gate+up GEMM, BK=64, 8 waves, 3-deep ring (144 KB LDS, 1 block/CU,
// 2 waves/SIMD). 2D XCD chunk (proven: FETCH 70->41 MB).
//   hh[n,h] = bf16( silu(x@gw^T) * (x@uw^T) )      K=1024.
// ---------------------------------------------------------------------------
__global__ __launch_bounds__(512)
void gup(const unsigned short* __restrict__ xh, const unsigned short* __restrict__ gwh,
         const unsigned short* __restrict__ uwh, unsigned short* __restrict__ hh)
{
    __shared__ __align__(16) unsigned short lds[73728];  // 3 bufs x (x|gw|uw 24576)
    const int tid = threadIdx.x;
    const int l   = tid & 63;
    const int w   = tid >> 6;
    const int wr  = w >> 2, wc = w & 3;

    int id  = blockIdx.y * gridDim.x + blockIdx.x;
    int xcd = id & 7, j = id >> 3;
    int bx  = (xcd & 1) * 8 + (j & 7);
    int by  = (xcd >> 1) * 8 + (j >> 3);
    const int bm0 = by * 128, bn0 = bx * 128;

    const int srow = tid >> 3;
    const int sq   = (tid & 7) ^ (srow & 7);
    const size_t aoff = (size_t)(bm0 + srow) * Dq + sq * 8;
    const size_t boff = (size_t)(bn0 + srow) * Dq + sq * 8;
    const size_t r64  = (size_t)64 * Dq;

    const int rowa = (wr * 64 + (l & 15)) * 64;
    const int rowb = (wc * 32 + (l & 15)) * 64;
    const int q0 = (((l >> 4)    ) ^ (l & 7)) << 3;
    const int q1 = (((l >> 4) + 4) ^ (l & 7)) << 3;

    auto stage = [&](int b, int kt) {          // 6 gl16
        unsigned short* d = &lds[b * 24576 + (w << 9)];
        gl16(xh  + aoff + kt,       d + 0);
        gl16(xh  + aoff + kt + r64, d + 4096);
        gl16(gwh + boff + kt,       d + 8192);
        gl16(gwh + boff + kt + r64, d + 12288);
        gl16(uwh + boff + kt,       d + 16384);
        gl16(uwh + boff + kt + r64, d + 20480);
    };

    f32x4 accg[4][2], accu[4][2];
#pragma unroll
    for (int i = 0; i < 4; i++)
#pragma unroll
        for (int jj = 0; jj < 2; jj++) {
            accg[i][jj] = (f32x4){0.f, 0.f, 0.f, 0.f};
            accu[i][jj] = (f32x4){0.f, 0.f, 0.f, 0.f};
        }

    stage(0, 0);
    stage(1, 64);
    int cur = 0;
    for (int kt = 0; kt < Dq; kt += 64) {
        // outstanding: buf(i) [6, oldest] + buf(i+1) [6]; in-order -> vmcnt(6)
        if (kt + 64 < Dq) { WAITV_BAR(6); } else { WAITV_BAR(0); }
        if (kt + 128 < Dq) {
            int nb3 = (cur + 2 >= 3) ? cur - 1 : cur + 2;
            stage(nb3, kt + 128);              // overwrites buf((i-1)%3): post-barrier safe
        }
        const int cb = cur * 24576;
#pragma unroll
        for (int ks = 0; ks < 2; ks++) {
            const int qo = ks ? q1 : q0;
            bfrag a4[4], g4[2], u4[2];
#pragma unroll
            for (int f = 0; f < 4; f++)
                a4[f] = *(const bfrag*)&lds[cb + rowa + f * 1024 + qo];
#pragma unroll
            for (int f = 0; f < 2; f++) {
                g4[f] = *(const bfrag*)&lds[cb +  8192 + rowb + f * 1024 + qo];
                u4[f] = *(const bfrag*)&lds[cb + 16384 + rowb + f * 1024 + qo];
            }
#pragma unroll
            for (int i = 0; i < 4; i++)
#pragma unroll
                for (int jj = 0; jj < 2; jj++) {
                    accg[i][jj] = __builtin_amdgcn_mfma_f32_16x16x32_bf16(a4[i], g4[jj], accg[i][jj], 0, 0, 0);
                    accu[i][jj] = __builtin_amdgcn_mfma_f32_16x16x32_bf16(a4[i], u4[jj], accu[i][jj], 0, 0, 0);
                }
        }
        cur = (cur == 2) ? 0 : cur + 1;
    }

    const int crow0 = bm0 + wr * 64 + (l >> 4) * 4;
    const int ccol0 = bn0 + wc * 32 + (l & 15);
#pragma unroll
    for (int i = 0; i < 4; i++)
#pragma unroll
        for (int jj = 0; jj < 2; jj++)
#pragma unroll
            for (int r = 0; r < 4; r++) {
                size_t idx = (size_t)(crow0 + i * 16 + r) * Hq + (ccol0 + jj * 16);
                hh[idx] = f2bf(silu_f(accg[i][jj][r]) * accu[i][jj][r]);
            }
}

// ---------------------------------------------------------------------------
// Final fused GEMM, BK=64, 8 waves, 3-deep ring (96 KB LDS, 1 block/CU,
// 2 waves/SIMD):  out[4096][1024] = hh@dwh^T (K=2048) + acat@kcat^T (K=256)
// ---------------------------------------------------------------------------
__global__ __launch_bounds__(512)
void gfinal(const unsigned short* __restrict__ hh, const unsigned short* __restrict__ dwh,
            const unsigned short* __restrict__ acat, const unsigned short* __restrict__ kcat,
            float* __restrict__ out)
{
    __shared__ __align__(16) unsigned short lds[49152];  // 3 bufs x 16384
    const int tid = threadIdx.x;
    const int l   = tid & 63;
    const int w   = tid >> 6;
    const int wr  = w >> 2, wc = w & 3;

    int nb  = gridDim.x * gridDim.y;                      // 256
    int id  = blockIdx.y * gridDim.x + blockIdx.x;
    int id2 = (id & 7) * (nb >> 3) + (id >> 3);
    int bx  = id2 % gridDim.x, by = id2 / gridDim.x;
    const int bm0 = by * 128, bn0 = bx * 128;

    const int srow = tid >> 3;
    const int sq   = (tid & 7) ^ (srow & 7);
    const int rowa = (wr * 64 + (l & 15)) * 64;
    const int rowb = (wc * 32 + (l & 15)) * 64;
    const int q0 = (((l >> 4)    ) ^ (l & 7)) << 3;
    const int q1 = (((l >> 4) + 4) ^ (l & 7)) << 3;

    f32x4 acc[4][2];
#pragma unroll
    for (int i = 0; i < 4; i++)
#pragma unroll
        for (int j = 0; j < 2; j++) acc[i][j] = (f32x4){0.f, 0.f, 0.f, 0.f};

    // ---- main: K=2048, 3-deep ----
    {
        const size_t aoff = (size_t)(bm0 + srow) * Hq + sq * 8;
        const size_t boff = (size_t)(bn0 + srow) * Hq + sq * 8;
        const size_t r64  = (size_t)64 * Hq;
        auto stage = [&](int b, int kt) {      // 4 gl16
            unsigned short* d = &lds[b * 16384 + (w << 9)];
            gl16(hh  + aoff + kt,       d + 0);
            gl16(hh  + aoff + kt + r64, d + 4096);
            gl16(dwh + boff + kt,       d + 8192);
            gl16(dwh + boff + kt + r64, d + 12288);
        };
        stage(0, 0);
        stage(1, 64);
        int cur = 0;
        for (int kt = 0; kt < Hq; kt += 64) {
            if (kt + 64 < Hq) { WAITV_BAR(4); } else { WAITV_BAR(0); }
            if (kt + 128 < Hq) {
                int nb3 = (cur + 2 >= 3) ? cur - 1 : cur + 2;
                stage(nb3, kt + 128);
            }
            const int cb = cur * 16384;
#pragma unroll
            for (int ks = 0; ks < 2; ks++) {
                const int qo = ks ? q1 : q0;
                bfrag a4[4], b4[2];
#pragma unroll
                for (int f = 0; f < 4; f++)
                    a4[f] = *(const bfrag*)&lds[cb + rowa + f * 1024 + qo];
#pragma unroll
                for (int f = 0; f < 2; f++)
                    b4[f] = *(const bfrag*)&lds[cb + 8192 + rowb + f * 1024 + qo];
#pragma unroll
                for (int i = 0; i < 4; i++)
#pragma unroll
                    for (int j = 0; j < 2; j++)
                        acc[i][j] = __builtin_amdgcn_mfma_f32_16x16x32_bf16(a4[i], b4[j], acc[i][j], 0, 0, 0);
            }
            cur = (cur == 2) ? 0 : cur + 1;
        }
    }
    END_BAR();   // all waves done with main's last compute before tail staging
    // ---- tail: K=256 over [acat | kcat], 3-deep (4 iters) ----
    {
        const size_t aoff = (size_t)(bm0 + srow) * 256 + sq * 8;
        const size_t boff = (size_t)(bn0 + srow) * 256 + sq * 8;
        const size_t r64  = (size_t)64 * 256;
        auto stage2 = [&](int b, int kt) {
            unsigned short* d = &lds[b * 16384 + (w << 9)];
            gl16(acat + aoff + kt,       d + 0);
            gl16(acat + aoff + kt + r64, d + 4096);
            gl16(kcat + boff + kt,       d + 8192);
            gl16(kcat + boff + kt + r64, d + 12288);
        };
        stage2(0, 0);
        stage2(1, 64);
        int cur = 0;
        for (int kt = 0; kt < 256; kt += 64) {
            if (kt + 64 < 256) { WAITV_BAR(4); } else { WAITV_BAR(0); }
            if (kt + 128 < 256) {
                int nb3 = (cur + 2 >= 3) ? cur - 1 : cur + 2;
                stage2(nb3, kt + 128);
            }
            const int cb = cur * 16384;
#pragma unroll
            for (int ks = 0; ks < 2; ks++) {
                const int qo = ks ? q1 : q0;
                bfrag a4[4], b4[2];
#pragma unroll
                for (int f = 0; f < 4; f++)
                    a4[f] = *(const bfrag*)&lds[cb + rowa + f * 1024 + qo];
#pragma unroll
                for (int f = 0; f < 2; f++)
                    b4[f] = *(const bfrag*)&lds[cb + 8192 + rowb + f * 1024 + qo];
#pragma unroll
                for (int i = 0; i < 4; i++)
#pragma unroll
                    for (int j = 0; j < 2; j++)
                        acc[i][j] = __builtin_amdgcn_mfma_f32_16x16x32_bf16(a4[i], b4[j], acc[i][j], 0, 0, 0);
            }
            cur = (cur == 2) ? 0 : cur + 1;
        }
    }

    const int crow0 = bm0 + wr * 64 + (l >> 4) * 4;
    const int ccol0 = bn0 + wc * 32 + (l & 15);
#pragma unroll
    for (int i = 0; i < 4; i++)
#pragma unroll
        for (int j = 0; j < 2; j++)
#pragma unroll
            for (int r = 0; r < 4; r++)
                out[(size_t)(crow0 + i * 16 + r) * Dq + ccol0 + j * 16] = acc[i][j][r];
}

// Reduce NZ split-K partials + LayerNorm over A=128 -> bf16.
template<int NZ>
__global__ __launch_bounds__(256)
void rln(const float* __restrict__ p, unsigned short* __restrict__ oh,
         const float* __restrict__ g, const float* __restrict__ b, long pstride)
{
    int row  = blockIdx.x * 4 + (threadIdx.x >> 6);
    int lane = threadIdx.x & 63;
    long base = (long)row * Aq;
    float x0 = 0.f, x1 = 0.f;
#pragma unroll
    for (int z = 0; z < NZ; z++) {
        x0 += p[base + z * pstride + lane];
        x1 += p[base + z * pstride + lane + 64];
    }
    float s  = x0 + x1;
    float ss = x0 * x0 + x1 * x1;
#pragma unroll
    for (int off = 32; off > 0; off >>= 1) {
        s  += __shfl_xor(s, off);
        ss += __shfl_xor(ss, off);
    }
    float m  = s * (1.0f / Aq);
    float v  = ss * (1.0f / Aq) - m * m;
    float rs = rsqrtf(v + 1e-5f);
    oh[base + lane]      = f2bf((x0 - m) * rs * g[lane]      + b[lane]);
    oh[base + lane + 64] = f2bf((x1 - m) * rs * g[lane + 64] + b[lane + 64]);
}

// Reduce NZ split-K partials [bz][NZ][rowsPerB][A] -> scaled bf16.
// Output col = ocol + bz*ocolStep (lets one launch fill both kcat halves).
template<int NZ>
__global__ __launch_bounds__(256)
void rbf(const float* __restrict__ p, unsigned short* __restrict__ o,
         int rowsPerB, float scale, int total, int ostride, int ocol, int ocolStep)
{
    int i = blockIdx.x * 256 + threadIdx.x;
    if (i >= total) return;
    int n = i >> 7, a = i & 127;
    int bz = n / rowsPerB, s = n - bz * rowsPerB;
    long base = ((long)bz * NZ) * rowsPerB * Aq + (long)s * Aq + a;
    float acc = 0.f;
#pragma unroll
    for (int z = 0; z < NZ; z++) acc += p[base + (long)z * rowsPerB * Aq];
    o[(long)s * ostride + (ocol + bz * ocolStep) + a +
      (ocolStep ? 0 : (long)bz * rowsPerB * ostride)] = f2bf(acc * scale);
}

// mixed[n,:] = sum_e ew[n,e] * LN_e(h[e,n,:])  -> bf16 into acat col 128.
__global__ __launch_bounds__(256)
void mix_ln(const float* __restrict__ h, const float* __restrict__ ew,
            const float* __restrict__ g, const float* __restrict__ bb,
            unsigned short* __restrict__ acat)
{
    int n    = blockIdx.x * 4 + (threadIdx.x >> 6);
    int lane = threadIdx.x & 63;
    float a0 = 0.0f, a1 = 0.0f;
#pragma unroll
    for (int e = 0; e < Eq; e++) {
        const float* r = h + ((long)e * Nq + n) * Aq;
        float x0 = r[lane], x1 = r[lane + 64];
        float s  = x0 + x1;
        float ss = x0 * x0 + x1 * x1;
#pragma unroll
        for (int off = 32; off > 0; off >>= 1) {
            s  += __shfl_xor(s, off);
            ss += __shfl_xor(ss, off);
        }
        float m  = s * (1.0f / Aq);
        float v  = ss * (1.0f / Aq) - m * m;
        float rs = rsqrtf(v + 1e-5f);
        float wv = ew[(long)n * Eq + e];
        a0 += wv * ((x0 - m) * rs * g[e * Aq + lane]      + bb[e * Aq + lane]);
        a1 += wv * ((x1 - m) * rs * g[e * Aq + lane + 64] + bb[e * Aq + lane + 64]);
    }
    acat[(long)n * 256 + 128 + lane]      = f2bf(a0);
    acat[(long)n * 256 + 128 + lane + 64] = f2bf(a1);
}

extern "C" void kernel_launch(void* const* d_in, const int* in_sizes, int n_in,
                              void* d_out, int out_size, void* d_ws, size_t ws_size,
                              hipStream_t stream)
{
    const float* x             = (const float*)d_in[0];
    const float* ew            = (const float*)d_in[1];
    const float* up_w          = (const float*)d_in[2];
    const float* gate_w        = (const float*)d_in[3];
    const float* down_w        = (const float*)d_in[4];
    const float* pre_w         = (const float*)d_in[5];
    const float* post_w        = (const float*)d_in[6];
    const float* an_g          = (const float*)d_in[7];
    const float* an_b          = (const float*)d_in[8];
    const float* adapt_proj_w  = (const float*)d_in[9];
    const float* adapter_w     = (const float*)d_in[10];
    const float* adapter_g     = (const float*)d_in[11];
    const float* adapter_b     = (const float*)d_in[12];
    const float* expert_proj_w = (const float*)d_in[13];
    const float* output_proj_w = (const float*)d_in[14];
    float* out = (float*)d_out;

    // ---- workspace (KB offsets; peak ~81 MB) ----
#define OFF(kb) ((char*)d_ws + (size_t)(kb) * 1024)
    float* kdp  = (float*)OFF(0);        // [16][D][A] 8MB   (phase 1, bz=0)
    float* wfp  = (float*)OFF(8192);     // 8MB              (phase 1, bz=1)
    float* p1   = (float*)OFF(16384);    // [8][N][A] 16MB   (phase 1)
    float* p2   = (float*)OFF(0);        // [8][N][A] 16MB   (phase 3)
    unsigned short* wmat = (unsigned short*)OFF(16384);  // [B][S][S] bf16 16MB (ph 3-4)
    float* p3   = (float*)OFF(0);        // [2][8][S][A] 16MB (phase 4)
    float* h_e  = (float*)OFF(0);        // [E][N][A] 16MB    (phase 5, after p3 dead)
    unsigned short* hh   = (unsigned short*)OFF(32768);  // [N,H] 16MB
    unsigned short* xh   = (unsigned short*)OFF(49152);  // 8MB
    unsigned short* gwh  = (unsigned short*)OFF(57344);  // 4MB
    unsigned short* uwh  = (unsigned short*)OFF(61440);  // 4MB
    unsigned short* dwh  = (unsigned short*)OFF(65536);  // 4MB   } contiguous pair
    unsigned short* oph  = (unsigned short*)OFF(69632);  // 4MB   } for batched kcat
    unsigned short* pwh  = (unsigned short*)OFF(73728);  // .25MB
    unsigned short* powh = (unsigned short*)OFF(73984);  // .5MB
    unsigned short* apT  = (unsigned short*)OFF(74496);  // .5MB  } contiguous pair
    unsigned short* epT  = (unsigned short*)OFF(75008);  // .5MB  }
    unsigned short* ainh = (unsigned short*)OFF(75520);  // 1MB
    unsigned short* ainT = (unsigned short*)OFF(76544);  // [B][A][S] 1MB
    unsigned short* aouth= (unsigned short*)OFF(77568);  // 1MB
    unsigned short* adw  = (unsigned short*)OFF(78592);  // .25MB
    unsigned short* kcat = (unsigned short*)OFF(78848);  // [D][256] .5MB
    unsigned short* acat = (unsigned short*)OFF(79360);  // [N][256] 2MB -> 81408
#undef OFF

    dim3 blk(256), blk512(512);
    const long NA = (long)Nq * Aq;
    const long SA = (long)Sq * Aq;
    const long SS = (long)Sq * Sq;

    // 1. conversions + transposes
    convert_all<<<dim3(2048), blk, 0, stream>>>(x, gate_w, up_w, down_w, pre_w, post_w,
        output_proj_w, adapter_w, xh, gwh, uwh, dwh, pwh, powh, oph, adw);
    transb<float><<<dim3(4, 64, 1), blk, 0, stream>>>(adapt_proj_w,  apT, Hq, Aq);
    transb<float><<<dim3(4, 64, 1), blk, 0, stream>>>(expert_proj_w, epT, Hq, Aq);

    // 2. weight fusions (batched bz=2): bz0 = dwh@apT -> kdp, bz1 = oph@epT -> wfp
    mg<0><<<dim3(1, 8, 32), blk512, 0, stream>>>(dwh, apT, kdp, Aq, Hq, 16,
        (long)Dq * Hq, (long)Aq * Hq, (long)16 * Dq * Aq, (long)Dq * Aq);
    rbf<16><<<dim3(1024), blk, 0, stream>>>(kdp, kcat, Dq, 1.0f, 2 * Dq * Aq, 256, 0, 128);

    // 3. ain = LN(x @ pre_w^T)  (split-K 8)
    mg<0><<<dim3(1, 32, 8), blk512, 0, stream>>>(xh, pwh, p1, Aq, Dq, 8, 0, 0, 0, NA);
    rln<8><<<dim3(1024), blk, 0, stream>>>(p1, ainh, an_g, an_b, NA);
    transb<unsigned short><<<dim3(4, 64, 2), blk, 0, stream>>>(ainh, ainT, Sq, Aq);

    // 4. fused SwiGLU: hh = bf16(silu(x@gw^T) * (x@uw^T))
    gup<<<dim3(16, 32), blk512, 0, stream>>>(xh, gwh, uwh, hh);

    // 5. aout = LN(hidden @ post_w^T)  (split-K 8)
    mg<0><<<dim3(1, 32, 8), blk512, 0, stream>>>(hh, powh, p2, Aq, Hq, 8, 0, 0, 0, NA);
    rln<8><<<dim3(1024), blk, 0, stream>>>(p2, aouth, an_g, an_b, NA);

    // 6. wmat = bf16(silu(clip(ain @ aout^T)))  per batch
    mg<1><<<dim3(16, 16, 2), blk512, 0, stream>>>(ainh, aouth, wmat, Sq, Aq, 1,
        SA, SA, SS, 0);

    // 7. acat[:,0:128] = 0.1 * (wmat @ ain)  (split-K 8, batched)
    mg<0><<<dim3(1, 16, 16), blk512, 0, stream>>>(wmat, ainT, p3, Aq, Sq, 8,
        SS, SA, 8 * SA, SA);
    rbf<8><<<dim3(2048), blk, 0, stream>>>(p3, acat, Sq, 0.1f, Nq * Aq, 256, 0, 0);

    // 8. expert path: h_e, then acat[:,128:256] = mixed
    mg<0><<<dim3(1, 32, 8), blk512, 0, stream>>>(ainh, adw, h_e, Aq, Aq, 1,
        0, (long)Aq * Aq, NA, 0);
    mix_ln<<<dim3(1024), blk, 0, stream>>>(h_e, ew, adapter_g, adapter_b, acat);

    // 9. out = hh@dwh^T + acat@kcat^T
    gfinal<<<dim3(8, 32), blk512, 0, stream>>>(hh, dwh, acat, kcat, out);
}

// Round 13
// 161.593 us; speedup vs baseline: 1.0540x; 1.0151x over previous
//
#include <hip/hip_runtime.h>
#include <hip/hip_bf16.h>
#include <math.h>

// Problem constants (B,S,D,E = 2,2048,1024,8)
#define Bq 2
#define Sq 2048
#define Dq 1024
#define Eq 8
#define Hq 2048            // 2*D
#define Aq 128             // H/16
#define Nq (Bq*Sq)         // 4096 tokens

typedef __attribute__((ext_vector_type(4))) float f32x4;
typedef __attribute__((ext_vector_type(8))) short bfrag;   // 8 bf16 in 4 VGPRs

__device__ __forceinline__ float silu_f(float x) {
    return x / (1.0f + expf(-x));
}
__device__ __forceinline__ unsigned short f2bf(float x) {  // RNE fp32->bf16
    unsigned u = __float_as_uint(x);
    u += 0x7fffu + ((u >> 16) & 1u);
    return (unsigned short)(u >> 16);
}
__device__ __forceinline__ float bf2f(unsigned short h) {
    return __uint_as_float(((unsigned)h) << 16);
}
__device__ __forceinline__ void gl16(const unsigned short* g, unsigned short* l) {
    __builtin_amdgcn_global_load_lds(
        (const __attribute__((address_space(1))) void*)g,
        (__attribute__((address_space(3))) void*)(void*)l, 16, 0, 0);
}

// Counted-vmcnt wait-then-barrier (T4). vmcnt retires IN ORDER.
#define WAITV_BAR(N)                                            \
    asm volatile("s_waitcnt vmcnt(" #N ")" ::: "memory");       \
    __builtin_amdgcn_s_barrier();                               \
    asm volatile("" ::: "memory")
#define END_BAR()                                               \
    asm volatile("" ::: "memory");                              \
    __builtin_amdgcn_s_barrier();                               \
    asm volatile("" ::: "memory")

// ---------------------------------------------------------------------------
// 512-thread / 8-wave BK=64 scheme:
//  Panel = [rows][64 cols] bf16, staged in rows/64 gl16 rounds
//  (srow = tid>>3 in 0..63, +64/round; slot sq = (tid&7)^(srow&7)).
//  LDS(row,q) holds G(row, q^(row&7)); conflict-free ds_read_b128 (proven 0).
//  Read slot qo = ((ks*4+(l>>4))^(l&7))*8; frag row base +(l&15) keeps
//  row&7 == l&7 so the same XOR recovers G.
// ---------------------------------------------------------------------------

__global__ __launch_bounds__(256)
void convert_all(const float* __restrict__ x,  const float* __restrict__ gw,
                 const float* __restrict__ uw, const float* __restrict__ dw,
                 const float* __restrict__ pw, const float* __restrict__ ow,
                 const float* __restrict__ opw, const float* __restrict__ aw,
                 unsigned short* xh,  unsigned short* gwh, unsigned short* uwh,
                 unsigned short* dwh, unsigned short* pwh, unsigned short* powh,
                 unsigned short* oph, unsigned short* adw)
{
    const int T = 3276800;
    for (int i = blockIdx.x * 256 + threadIdx.x; i < T; i += gridDim.x * 256) {
        const float* in; unsigned short* hi; int j = i;
        if (j < 1048576)                 { in = x;   hi = xh;  }
        else if ((j -= 1048576) < 524288){ in = gw;  hi = gwh; }
        else if ((j -= 524288) < 524288) { in = uw;  hi = uwh; }
        else if ((j -= 524288) < 524288) { in = dw;  hi = dwh; }
        else if ((j -= 524288) < 32768)  { in = pw;  hi = pwh; }
        else if ((j -= 32768) < 65536)   { in = ow;  hi = powh; }
        else if ((j -= 65536) < 524288)  { in = opw; hi = oph; }
        else { j -= 524288;                in = aw;  hi = adw; }
        float4 v = ((const float4*)in)[j];
        ((ushort4*)hi)[j] = make_ushort4(f2bf(v.x), f2bf(v.y), f2bf(v.z), f2bf(v.w));
    }
}

// Transpose [R][C] -> bf16 [C][R], batched by blockIdx.z.
template<typename TIN>
__global__ __launch_bounds__(256)
void transb(const TIN* __restrict__ in, unsigned short* __restrict__ out, int R, int C)
{
    __shared__ float t[32][33];
    in  += (size_t)blockIdx.z * R * C;
    out += (size_t)blockIdx.z * R * C;
    int tx = threadIdx.x & 31, ty = threadIdx.x >> 5;
    int r0 = blockIdx.y * 32, c0 = blockIdx.x * 32;
#pragma unroll
    for (int j = 0; j < 4; j++) {
        TIN v = in[(size_t)(r0 + ty + j * 8) * C + c0 + tx];
        float f;
        if (sizeof(TIN) == 2) f = bf2f(*(const unsigned short*)&v);
        else                  f = *(const float*)&v;
        t[ty + j * 8][tx] = f;
    }
    __syncthreads();
#pragma unroll
    for (int j = 0; j < 4; j++)
        out[(size_t)(c0 + ty + j * 8) * R + r0 + tx] = f2bf(t[tx][ty + j * 8]);
}

// ---------------------------------------------------------------------------
// 1-term bf16 MFMA GEMM, BK=64, 8 waves (2Mx4N, wave tile 64x32), 2-buf +
// counted-vmcnt. 64 KB LDS -> 2 blocks/CU -> 4 waves/SIMD.
// EPI: 0 = fp32 store (+bz*zC+kz*pz); 1 = bf16 silu-clip store (+bz*zC).
// ---------------------------------------------------------------------------
template<int EPI>
__global__ __launch_bounds__(512)
void mg(const unsigned short* __restrict__ Ah, const unsigned short* __restrict__ Bh,
        void* __restrict__ Cv, int N, int K, int kchunks,
        long zA, long zB, long zC, long pz)
{
    __shared__ __align__(16) unsigned short lds[32768];  // 2 bufs x (A 8192 | B 8192)

    const int tid = threadIdx.x;
    const int l   = tid & 63;
    const int w   = tid >> 6;                  // 0..7
    const int wr  = w >> 2, wc = w & 3;
    const int bm0 = blockIdx.y * 128, bn0 = blockIdx.x * 128;
    const int bz  = blockIdx.z / kchunks;
    const int kz  = blockIdx.z - bz * kchunks;
    const int kcnt = K / kchunks;
    const int kbeg = kz * kcnt;
    const int kend = kbeg + kcnt;

    const unsigned short* A0 = Ah + (size_t)bz * zA;
    const unsigned short* B0 = Bh + (size_t)bz * zB;

    const int srow = tid >> 3;                 // 0..63 (+64 round 1)
    const int sq   = (tid & 7) ^ (srow & 7);
    const size_t aoff = (size_t)(bm0 + srow) * K + sq * 8;
    const size_t boff = (size_t)(bn0 + srow) * K + sq * 8;
    const size_t r64  = (size_t)64 * K;

    auto stage = [&](int b, int kt) {          // 4 gl16
        unsigned short* d = &lds[b * 16384 + (w << 9)];
        gl16(A0 + aoff + kt,       d + 0);
        gl16(A0 + aoff + kt + r64, d + 4096);
        gl16(B0 + boff + kt,       d + 8192);
        gl16(B0 + boff + kt + r64, d + 12288);
    };

    const int rowa = (wr * 64 + (l & 15)) * 64;
    const int rowb = (wc * 32 + (l & 15)) * 64;
    const int q0 = (((l >> 4)    ) ^ (l & 7)) << 3;
    const int q1 = (((l >> 4) + 4) ^ (l & 7)) << 3;

    f32x4 acc[4][2];
#pragma unroll
    for (int i = 0; i < 4; i++)
#pragma unroll
        for (int j = 0; j < 2; j++) acc[i][j] = (f32x4){0.f, 0.f, 0.f, 0.f};

    stage(0, kbeg);
    int cur = 0;
    for (int kt = kbeg; kt < kend; kt += 64) {
        if (kt + 64 < kend) {
            stage(cur ^ 1, kt + 64);
            WAITV_BAR(4);
        } else {
            WAITV_BAR(0);
        }
        const int cb = cur * 16384;
#pragma unroll
        for (int ks = 0; ks < 2; ks++) {
            const int qo = ks ? q1 : q0;
            bfrag a4[4], b4[2];
#pragma unroll
            for (int f = 0; f < 4; f++)
                a4[f] = *(const bfrag*)&lds[cb + rowa + f * 1024 + qo];
#pragma unroll
            for (int f = 0; f < 2; f++)
                b4[f] = *(const bfrag*)&lds[cb + 8192 + rowb + f * 1024 + qo];
#pragma unroll
            for (int i = 0; i < 4; i++)
#pragma unroll
                for (int j = 0; j < 2; j++)
                    acc[i][j] = __builtin_amdgcn_mfma_f32_16x16x32_bf16(a4[i], b4[j], acc[i][j], 0, 0, 0);
        }
        END_BAR();
        cur ^= 1;
    }

    const int crow0 = bm0 + wr * 64 + (l >> 4) * 4;
    const int ccol0 = bn0 + wc * 32 + (l & 15);
#pragma unroll
    for (int i = 0; i < 4; i++)
#pragma unroll
        for (int j = 0; j < 2; j++)
#pragma unroll
            for (int r = 0; r < 4; r++) {
                size_t idx = (size_t)(crow0 + i * 16 + r) * N + (ccol0 + j * 16);
                float v = acc[i][j][r];
                if (EPI == 0)
                    ((float*)Cv + (size_t)bz * zC + (size_t)kz * pz)[idx] = v;
                else
                    ((unsigned short*)Cv + (size_t)bz * zC)[idx] =
                        f2bf(silu_f(fminf(fmaxf(v, -5.f), 5.f)));
            }
}

// ---------------------------------------------------------------------------
// Fused gate+up GEMM, tile 256x128, BK=64, 8 waves (4Mx2N, wave tile 64x64),
// 2-buf + counted-vmcnt. Intensity 128 FLOP/B (1.5x the 128x128 version) —
// round-12 showed gup is staging-BW-bound (1.5 MB/CU @ 33 GB/s/CU).
// Grid 16x16 = 256 blocks = 1/CU; LDS 2 x 64 KB. 2D XCD chunk: 4bx x 8by.
//   hh[n,h] = bf16( silu(x@gw^T) * (x@uw^T) )      K=1024.
// ---------------------------------------------------------------------------
__global__ __launch_bounds__(512)
void gup(const unsigned short* __restrict__ xh, const unsigned short* __restrict__ gwh,
         const unsigned short* __restrict__ uwh, unsigned short* __restrict__ hh)
{
    __shared__ __align__(16) unsigned short lds[65536];  // 2 bufs x (x32K|gw16K|uw16K)
    const int tid = threadIdx.x;
    const int l   = tid & 63;
    const int w   = tid >> 6;
    const int wr  = w >> 1, wc = w & 1;        // 4 row-waves x 2 col-waves

    int id  = blockIdx.y * gridDim.x + blockIdx.x;     // grid (16,16)
    int xcd = id & 7, j = id >> 3;                     // j in 0..31
    int bx  = (xcd & 3) * 4 + (j & 3);                 // 0..15
    int by  = (xcd >> 2) * 8 + (j >> 2);               // 0..15
    const int bm0 = by * 256, bn0 = bx * 128;

    const int srow = tid >> 3;                 // 0..63
    const int sq   = (tid & 7) ^ (srow & 7);
    const size_t aoff = (size_t)(bm0 + srow) * Dq + sq * 8;
    const size_t boff = (size_t)(bn0 + srow) * Dq + sq * 8;
    const size_t r64  = (size_t)64 * Dq;

    const int rowa = (wr * 64 + (l & 15)) * 64;   // x rows 0..255 (frag +i*1024)
    const int rowb = (wc * 64 + (l & 15)) * 64;   // w rows 0..127 (frag +j*1024)
    const int q0 = (((l >> 4)    ) ^ (l & 7)) << 3;
    const int q1 = (((l >> 4) + 4) ^ (l & 7)) << 3;

    auto stage = [&](int b, int kt) {          // 8 gl16: x(4 rounds), gw(2), uw(2)
        unsigned short* d = &lds[b * 32768 + (w << 9)];
        gl16(xh  + aoff + kt,           d + 0);
        gl16(xh  + aoff + kt + r64,     d + 4096);
        gl16(xh  + aoff + kt + 2 * r64, d + 8192);
        gl16(xh  + aoff + kt + 3 * r64, d + 12288);
        gl16(gwh + boff + kt,           d + 16384);
        gl16(gwh + boff + kt + r64,     d + 20480);
        gl16(uwh + boff + kt,           d + 24576);
        gl16(uwh + boff + kt + r64,     d + 28672);
    };

    f32x4 accg[4][4], accu[4][4];
#pragma unroll
    for (int i = 0; i < 4; i++)
#pragma unroll
        for (int jj = 0; jj < 4; jj++) {
            accg[i][jj] = (f32x4){0.f, 0.f, 0.f, 0.f};
            accu[i][jj] = (f32x4){0.f, 0.f, 0.f, 0.f};
        }

    stage(0, 0);
    int cur = 0;
    for (int kt = 0; kt < Dq; kt += 64) {
        if (kt + 64 < Dq) {
            stage(cur ^ 1, kt + 64);       // next tile's 8 loads stay in flight
            WAITV_BAR(8);                  // drain only CUR's 8 (in-order retire)
        } else {
            WAITV_BAR(0);
        }
        const int cb = cur * 32768;
#pragma unroll
        for (int ks = 0; ks < 2; ks++) {
            const int qo = ks ? q1 : q0;
            bfrag a4[4], g4[4], u4[4];
#pragma unroll
            for (int f = 0; f < 4; f++) {
                a4[f] = *(const bfrag*)&lds[cb +         rowa + f * 1024 + qo];
                g4[f] = *(const bfrag*)&lds[cb + 16384 + rowb + f * 1024 + qo];
                u4[f] = *(const bfrag*)&lds[cb + 24576 + rowb + f * 1024 + qo];
            }
#pragma unroll
            for (int i = 0; i < 4; i++)
#pragma unroll
                for (int jj = 0; jj < 4; jj++) {
                    accg[i][jj] = __builtin_amdgcn_mfma_f32_16x16x32_bf16(a4[i], g4[jj], accg[i][jj], 0, 0, 0);
                    accu[i][jj] = __builtin_amdgcn_mfma_f32_16x16x32_bf16(a4[i], u4[jj], accu[i][jj], 0, 0, 0);
                }
        }
        END_BAR();                         // readers done before next overwrite
        cur ^= 1;
    }

    const int crow0 = bm0 + wr * 64 + (l >> 4) * 4;
    const int ccol0 = bn0 + wc * 64 + (l & 15);
#pragma unroll
    for (int i = 0; i < 4; i++)
#pragma unroll
        for (int jj = 0; jj < 4; jj++)
#pragma unroll
            for (int r = 0; r < 4; r++) {
                size_t idx = (size_t)(crow0 + i * 16 + r) * Hq + (ccol0 + jj * 16);
                hh[idx] = f2bf(silu_f(accg[i][jj][r]) * accu[i][jj][r]);
            }
}

// ---------------------------------------------------------------------------
// Final fused GEMM, BK=64, 8 waves (2Mx4N), 3-deep ring (96 KB LDS, 1 block/CU,
// 2 waves/SIMD):  out[4096][1024] = hh@dwh^T (K=2048) + acat@kcat^T (K=256)
// ---------------------------------------------------------------------------
__global__ __launch_bounds__(512)
void gfinal(const unsigned short* __restrict__ hh, const unsigned short* __restrict__ dwh,
            const unsigned short* __restrict__ acat, const unsigned short* __restrict__ kcat,
            float* __restrict__ out)
{
    __shared__ __align__(16) unsigned short lds[49152];  // 3 bufs x 16384
    const int tid = threadIdx.x;
    const int l   = tid & 63;
    const int w   = tid >> 6;
    const int wr  = w >> 2, wc = w & 3;

    int nb  = gridDim.x * gridDim.y;                      // 256
    int id  = blockIdx.y * gridDim.x + blockIdx.x;
    int id2 = (id & 7) * (nb >> 3) + (id >> 3);
    int bx  = id2 % gridDim.x, by = id2 / gridDim.x;
    const int bm0 = by * 128, bn0 = bx * 128;

    const int srow = tid >> 3;
    const int sq   = (tid & 7) ^ (srow & 7);
    const int rowa = (wr * 64 + (l & 15)) * 64;
    const int rowb = (wc * 32 + (l & 15)) * 64;
    const int q0 = (((l >> 4)    ) ^ (l & 7)) << 3;
    const int q1 = (((l >> 4) + 4) ^ (l & 7)) << 3;

    f32x4 acc[4][2];
#pragma unroll
    for (int i = 0; i < 4; i++)
#pragma unroll
        for (int j = 0; j < 2; j++) acc[i][j] = (f32x4){0.f, 0.f, 0.f, 0.f};

    // ---- main: K=2048, 3-deep ----
    {
        const size_t aoff = (size_t)(bm0 + srow) * Hq + sq * 8;
        const size_t boff = (size_t)(bn0 + srow) * Hq + sq * 8;
        const size_t r64  = (size_t)64 * Hq;
        auto stage = [&](int b, int kt) {      // 4 gl16
            unsigned short* d = &lds[b * 16384 + (w << 9)];
            gl16(hh  + aoff + kt,       d + 0);
            gl16(hh  + aoff + kt + r64, d + 4096);
            gl16(dwh + boff + kt,       d + 8192);
            gl16(dwh + boff + kt + r64, d + 12288);
        };
        stage(0, 0);
        stage(1, 64);
        int cur = 0;
        for (int kt = 0; kt < Hq; kt += 64) {
            if (kt + 64 < Hq) { WAITV_BAR(4); } else { WAITV_BAR(0); }
            if (kt + 128 < Hq) {
                int nb3 = (cur + 2 >= 3) ? cur - 1 : cur + 2;
                stage(nb3, kt + 128);
            }
            const int cb = cur * 16384;
#pragma unroll
            for (int ks = 0; ks < 2; ks++) {
                const int qo = ks ? q1 : q0;
                bfrag a4[4], b4[2];
#pragma unroll
                for (int f = 0; f < 4; f++)
                    a4[f] = *(const bfrag*)&lds[cb + rowa + f * 1024 + qo];
#pragma unroll
                for (int f = 0; f < 2; f++)
                    b4[f] = *(const bfrag*)&lds[cb + 8192 + rowb + f * 1024 + qo];
#pragma unroll
                for (int i = 0; i < 4; i++)
#pragma unroll
                    for (int j = 0; j < 2; j++)
                        acc[i][j] = __builtin_amdgcn_mfma_f32_16x16x32_bf16(a4[i], b4[j], acc[i][j], 0, 0, 0);
            }
            cur = (cur == 2) ? 0 : cur + 1;
        }
    }
    END_BAR();   // all waves done with main's last compute before tail staging
    // ---- tail: K=256 over [acat | kcat], 3-deep (4 iters) ----
    {
        const size_t aoff = (size_t)(bm0 + srow) * 256 + sq * 8;
        const size_t boff = (size_t)(bn0 + srow) * 256 + sq * 8;
        const size_t r64  = (size_t)64 * 256;
        auto stage2 = [&](int b, int kt) {
            unsigned short* d = &lds[b * 16384 + (w << 9)];
            gl16(acat + aoff + kt,       d + 0);
            gl16(acat + aoff + kt + r64, d + 4096);
            gl16(kcat + boff + kt,       d + 8192);
            gl16(kcat + boff + kt + r64, d + 12288);
        };
        stage2(0, 0);
        stage2(1, 64);
        int cur = 0;
        for (int kt = 0; kt < 256; kt += 64) {
            if (kt + 64 < 256) { WAITV_BAR(4); } else { WAITV_BAR(0); }
            if (kt + 128 < 256) {
                int nb3 = (cur + 2 >= 3) ? cur - 1 : cur + 2;
                stage2(nb3, kt + 128);
            }
            const int cb = cur * 16384;
#pragma unroll
            for (int ks = 0; ks < 2; ks++) {
                const int qo = ks ? q1 : q0;
                bfrag a4[4], b4[2];
#pragma unroll
                for (int f = 0; f < 4; f++)
                    a4[f] = *(const bfrag*)&lds[cb + rowa + f * 1024 + qo];
#pragma unroll
                for (int f = 0; f < 2; f++)
                    b4[f] = *(const bfrag*)&lds[cb + 8192 + rowb + f * 1024 + qo];
#pragma unroll
                for (int i = 0; i < 4; i++)
#pragma unroll
                    for (int j = 0; j < 2; j++)
                        acc[i][j] = __builtin_amdgcn_mfma_f32_16x16x32_bf16(a4[i], b4[j], acc[i][j], 0, 0, 0);
            }
            cur = (cur == 2) ? 0 : cur + 1;
        }
    }

    const int crow0 = bm0 + wr * 64 + (l >> 4) * 4;
    const int ccol0 = bn0 + wc * 32 + (l & 15);
#pragma unroll
    for (int i = 0; i < 4; i++)
#pragma unroll
        for (int j = 0; j < 2; j++)
#pragma unroll
            for (int r = 0; r < 4; r++)
                out[(size_t)(crow0 + i * 16 + r) * Dq + ccol0 + j * 16] = acc[i][j][r];
}

// Reduce NZ split-K partials + LayerNorm over A=128 -> bf16.
template<int NZ>
__global__ __launch_bounds__(256)
void rln(const float* __restrict__ p, unsigned short* __restrict__ oh,
         const float* __restrict__ g, const float* __restrict__ b, long pstride)
{
    int row  = blockIdx.x * 4 + (threadIdx.x >> 6);
    int lane = threadIdx.x & 63;
    long base = (long)row * Aq;
    float x0 = 0.f, x1 = 0.f;
#pragma unroll
    for (int z = 0; z < NZ; z++) {
        x0 += p[base + z * pstride + lane];
        x1 += p[base + z * pstride + lane + 64];
    }
    float s  = x0 + x1;
    float ss = x0 * x0 + x1 * x1;
#pragma unroll
    for (int off = 32; off > 0; off >>= 1) {
        s  += __shfl_xor(s, off);
        ss += __shfl_xor(ss, off);
    }
    float m  = s * (1.0f / Aq);
    float v  = ss * (1.0f / Aq) - m * m;
    float rs = rsqrtf(v + 1e-5f);
    oh[base + lane]      = f2bf((x0 - m) * rs * g[lane]      + b[lane]);
    oh[base + lane + 64] = f2bf((x1 - m) * rs * g[lane + 64] + b[lane + 64]);
}

// Reduce NZ split-K partials [bz][NZ][rowsPerB][A] -> scaled bf16.
// Output col = ocol + bz*ocolStep (lets one launch fill both kcat halves).
template<int NZ>
__global__ __launch_bounds__(256)
void rbf(const float* __restrict__ p, unsigned short* __restrict__ o,
         int rowsPerB, float scale, int total, int ostride, int ocol, int ocolStep)
{
    int i = blockIdx.x * 256 + threadIdx.x;
    if (i >= total) return;
    int n = i >> 7, a = i & 127;
    int bz = n / rowsPerB, s = n - bz * rowsPerB;
    long base = ((long)bz * NZ) * rowsPerB * Aq + (long)s * Aq + a;
    float acc = 0.f;
#pragma unroll
    for (int z = 0; z < NZ; z++) acc += p[base + (long)z * rowsPerB * Aq];
    o[(long)s * ostride + (ocol + bz * ocolStep) + a +
      (ocolStep ? 0 : (long)bz * rowsPerB * ostride)] = f2bf(acc * scale);
}

// mixed[n,:] = sum_e ew[n,e] * LN_e(h[e,n,:])  -> bf16 into acat col 128.
__global__ __launch_bounds__(256)
void mix_ln(const float* __restrict__ h, const float* __restrict__ ew,
            const float* __restrict__ g, const float* __restrict__ bb,
            unsigned short* __restrict__ acat)
{
    int n    = blockIdx.x * 4 + (threadIdx.x >> 6);
    int lane = threadIdx.x & 63;
    float a0 = 0.0f, a1 = 0.0f;
#pragma unroll
    for (int e = 0; e < Eq; e++) {
        const float* r = h + ((long)e * Nq + n) * Aq;
        float x0 = r[lane], x1 = r[lane + 64];
        float s  = x0 + x1;
        float ss = x0 * x0 + x1 * x1;
#pragma unroll
        for (int off = 32; off > 0; off >>= 1) {
            s  += __shfl_xor(s, off);
            ss += __shfl_xor(ss, off);
        }
        float m  = s * (1.0f / Aq);
        float v  = ss * (1.0f / Aq) - m * m;
        float rs = rsqrtf(v + 1e-5f);
        float wv = ew[(long)n * Eq + e];
        a0 += wv * ((x0 - m) * rs * g[e * Aq + lane]      + bb[e * Aq + lane]);
        a1 += wv * ((x1 - m) * rs * g[e * Aq + lane + 64] + bb[e * Aq + lane + 64]);
    }
    acat[(long)n * 256 + 128 + lane]      = f2bf(a0);
    acat[(long)n * 256 + 128 + lane + 64] = f2bf(a1);
}

extern "C" void kernel_launch(void* const* d_in, const int* in_sizes, int n_in,
                              void* d_out, int out_size, void* d_ws, size_t ws_size,
                              hipStream_t stream)
{
    const float* x             = (const float*)d_in[0];
    const float* ew            = (const float*)d_in[1];
    const float* up_w          = (const float*)d_in[2];
    const float* gate_w       = (const float*)d_in[3];
    const float* down_w        = (const float*)d_in[4];
    const float* pre_w         = (const float*)d_in[5];
    const float* post_w        = (const float*)d_in[6];
    const float* an_g          = (const float*)d_in[7];
    const float* an_b          = (const float*)d_in[8];
    const float* adapt_proj_w  = (const float*)d_in[9];
    const float* adapter_w     = (const float*)d_in[10];
    const float* adapter_g     = (const float*)d_in[11];
    const float* adapter_b     = (const float*)d_in[12];
    const float* expert_proj_w = (const float*)d_in[13];
    const float* output_proj_w = (const float*)d_in[14];
    float* out = (float*)d_out;

    // ---- workspace (KB offsets; peak ~81 MB) ----
#define OFF(kb) ((char*)d_ws + (size_t)(kb) * 1024)
    float* kdp  = (float*)OFF(0);        // [16][D][A] 8MB   (phase 1, bz=0)
    float* wfp  = (float*)OFF(8192);     // 8MB              (phase 1, bz=1)
    float* p1   = (float*)OFF(16384);    // [8][N][A] 16MB   (phase 1)
    float* p2   = (float*)OFF(0);        // [8][N][A] 16MB   (phase 3)
    unsigned short* wmat = (unsigned short*)OFF(16384);  // [B][S][S] bf16 16MB (ph 3-4)
    float* p3   = (float*)OFF(0);        // [2][8][S][A] 16MB (phase 4)
    float* h_e  = (float*)OFF(0);        // [E][N][A] 16MB    (phase 5, after p3 dead)
    unsigned short* hh   = (unsigned short*)OFF(32768);  // [N,H] 16MB
    unsigned short* xh   = (unsigned short*)OFF(49152);  // 8MB
    unsigned short* gwh  = (unsigned short*)OFF(57344);  // 4MB
    unsigned short* uwh  = (unsigned short*)OFF(61440);  // 4MB
    unsigned short* dwh  = (unsigned short*)OFF(65536);  // 4MB   } contiguous pair
    unsigned short* oph  = (unsigned short*)OFF(69632);  // 4MB   } for batched kcat
    unsigned short* pwh  = (unsigned short*)OFF(73728);  // .25MB
    unsigned short* powh = (unsigned short*)OFF(73984);  // .5MB
    unsigned short* apT  = (unsigned short*)OFF(74496);  // .5MB  } contiguous pair
    unsigned short* epT  = (unsigned short*)OFF(75008);  // .5MB  }
    unsigned short* ainh = (unsigned short*)OFF(75520);  // 1MB
    unsigned short* ainT = (unsigned short*)OFF(76544);  // [B][A][S] 1MB
    unsigned short* aouth= (unsigned short*)OFF(77568);  // 1MB
    unsigned short* adw  = (unsigned short*)OFF(78592);  // .25MB
    unsigned short* kcat = (unsigned short*)OFF(78848);  // [D][256] .5MB
    unsigned short* acat = (unsigned short*)OFF(79360);  // [N][256] 2MB -> 81408
#undef OFF

    dim3 blk(256), blk512(512);
    const long NA = (long)Nq * Aq;
    const long SA = (long)Sq * Aq;
    const long SS = (long)Sq * Sq;

    // 1. conversions + transposes
    convert_all<<<dim3(2048), blk, 0, stream>>>(x, gate_w, up_w, down_w, pre_w, post_w,
        output_proj_w, adapter_w, xh, gwh, uwh, dwh, pwh, powh, oph, adw);
    transb<float><<<dim3(4, 64, 1), blk, 0, stream>>>(adapt_proj_w,  apT, Hq, Aq);
    transb<float><<<dim3(4, 64, 1), blk, 0, stream>>>(expert_proj_w, epT, Hq, Aq);

    // 2. weight fusions (batched bz=2): bz0 = dwh@apT -> kdp, bz1 = oph@epT -> wfp
    mg<0><<<dim3(1, 8, 32), blk512, 0, stream>>>(dwh, apT, kdp, Aq, Hq, 16,
        (long)Dq * Hq, (long)Aq * Hq, (long)16 * Dq * Aq, (long)Dq * Aq);
    rbf<16><<<dim3(1024), blk, 0, stream>>>(kdp, kcat, Dq, 1.0f, 2 * Dq * Aq, 256, 0, 128);

    // 3. ain = LN(x @ pre_w^T)  (split-K 8)
    mg<0><<<dim3(1, 32, 8), blk512, 0, stream>>>(xh, pwh, p1, Aq, Dq, 8, 0, 0, 0, NA);
    rln<8><<<dim3(1024), blk, 0, stream>>>(p1, ainh, an_g, an_b, NA);
    transb<unsigned short><<<dim3(4, 64, 2), blk, 0, stream>>>(ainh, ainT, Sq, Aq);

    // 4. fused SwiGLU: hh = bf16(silu(x@gw^T) * (x@uw^T))   tile 256x128
    gup<<<dim3(16, 16), blk512, 0, stream>>>(xh, gwh, uwh, hh);

    // 5. aout = LN(hidden @ post_w^T)  (split-K 8)
    mg<0><<<dim3(1, 32, 8), blk512, 0, stream>>>(hh, powh, p2, Aq, Hq, 8, 0, 0, 0, NA);
    rln<8><<<dim3(1024), blk, 0, stream>>>(p2, aouth, an_g, an_b, NA);

    // 6. wmat = bf16(silu(clip(ain @ aout^T)))  per batch
    mg<1><<<dim3(16, 16, 2), blk512, 0, stream>>>(ainh, aouth, wmat, Sq, Aq, 1,
        SA, SA, SS, 0);

    // 7. acat[:,0:128] = 0.1 * (wmat @ ain)  (split-K 8, batched)
    mg<0><<<dim3(1, 16, 16), blk512, 0, stream>>>(wmat, ainT, p3, Aq, Sq, 8,
        SS, SA, 8 * SA, SA);
    rbf<8><<<dim3(2048), blk, 0, stream>>>(p3, acat, Sq, 0.1f, Nq * Aq, 256, 0, 0);

    // 8. expert path: h_e, then acat[:,128:256] = mixed
    mg<0><<<dim3(1, 32, 8), blk512, 0, stream>>>(ainh, adw, h_e, Aq, Aq, 1,
        0, (long)Aq * Aq, NA, 0);
    mix_ln<<<dim3(1024), blk, 0, stream>>>(h_e, ew, adapter_g, adapter_b, acat);

    // 9. out = hh@dwh^T + acat@kcat^T
    gfinal<<<dim3(8, 32), blk512, 0, stream>>>(hh, dwh, acat, kcat, out);
}